// Round 13
// baseline (96.250 us; speedup 1.0000x reference)
//
#include <hip/hip_runtime.h>
#include <hip/hip_bf16.h>

#define Bsz 4
#define Ssz 2048
#define Dsz 256
#define Hh 8
#define HDd 32

typedef __attribute__((ext_vector_type(8))) short bh8;
typedef __attribute__((ext_vector_type(4))) float f4;
typedef __attribute__((ext_vector_type(4))) unsigned u4;
typedef __attribute__((ext_vector_type(2))) unsigned u2;

#define SCAL 0.17677669529663687f   /* 32^-0.5 */
#define LOG2E 1.4426950408889634f
#define QSCALE (SCAL * LOG2E)

__device__ __forceinline__ short f2bf(float f) {
    union { float f; unsigned u; } x; x.f = f;
    unsigned r = x.u + 0x7fffu + ((x.u >> 16) & 1u);
    return (short)(r >> 16);
}

__device__ __forceinline__ float bf2f(short s) {
    union { unsigned u; float f; } x;
    x.u = ((unsigned)(unsigned short)s) << 16;
    return x.f;
}

__device__ __forceinline__ float fexp2(float x) {
#if __has_builtin(__builtin_amdgcn_exp2f)
    return __builtin_amdgcn_exp2f(x);
#else
    float r; asm("v_exp_f32 %0, %1" : "=v"(r) : "v"(x)); return r;
#endif
}

__device__ __forceinline__ unsigned cvtpk(float lo, float hi) {
    unsigned r; asm("v_cvt_pk_bf16_f32 %0, %1, %2" : "=v"(r) : "v"(lo), "v"(hi));
    return r;
}

__device__ __forceinline__ void gload16(const void* g, void* l) {
    __builtin_amdgcn_global_load_lds(
        (const __attribute__((address_space(1))) unsigned int*)g,
        (__attribute__((address_space(3))) unsigned int*)l, 16, 0, 0);
}

// ---------------- prep: fragment-packed weights + hp/hv bf16 + flag zero ----------------
// Wf layout per matrix (65536 shorts): [k0g=d>>5][ntile=n>>4][lane=((d>>3)&3)*16+(n&15)][j=d&7]
__global__ __launch_bounds__(256) void prep_fast(
    const float* __restrict__ hid, const float* __restrict__ pos,
    const float* __restrict__ Wq, const float* __restrict__ Wk,
    const float* __restrict__ Wv, const float* __restrict__ Wo,
    const float* __restrict__ bq,
    short* __restrict__ Wf, float* __restrict__ bqs,
    short* __restrict__ hp, short* __restrict__ hv,
    int* __restrict__ flag)
{
    const int bid = blockIdx.x;
    if (bid < 256) {
        int t = bid * 256 + threadIdx.x;   // t = d*256 + n
        int d = t >> 8, n = t & 255;
        int off = (((d >> 5) * 16 + (n >> 4)) * 64 + ((d >> 3) & 3) * 16 + (n & 15)) * 8 + (d & 7);
        Wf[off]          = f2bf(Wq[t] * QSCALE);
        Wf[65536 + off]  = f2bf(Wk[t]);
        Wf[131072 + off] = f2bf(Wv[t]);
        Wf[196608 + off] = f2bf(Wo[t]);
        if (t == 0) *flag = 0;
        if (t < 256) bqs[t] = bq[t] * QSCALE;
    } else {
        const size_t i = ((size_t)(bid - 256) * 256 + threadIdx.x) * 8;
        f4 h1 = *(const f4*)(hid + i), h2 = *(const f4*)(hid + i + 4);
        f4 p1 = *(const f4*)(pos + i), p2 = *(const f4*)(pos + i + 4);
        union { unsigned u[4]; bh8 v; } a, b;
        a.u[0] = cvtpk(h1[0] + p1[0], h1[1] + p1[1]);
        a.u[1] = cvtpk(h1[2] + p1[2], h1[3] + p1[3]);
        a.u[2] = cvtpk(h2[0] + p2[0], h2[1] + p2[1]);
        a.u[3] = cvtpk(h2[2] + p2[2], h2[3] + p2[3]);
        b.u[0] = cvtpk(h1[0], h1[1]); b.u[1] = cvtpk(h1[2], h1[3]);
        b.u[2] = cvtpk(h2[0], h2[1]); b.u[3] = cvtpk(h2[2], h2[3]);
        *(bh8*)(hp + i) = a.v;
        *(bh8*)(hv + i) = b.v;
    }
}

// ---------------- fused QKV projection + mask scan ----------------
// blocks [0,256): gemm, 32 rows/block, all 3 projections, LDS-staged A (swizzled);
// blocks [256,1280): mask scan (lane-contiguous, 16 independent 1KB-coalesced loads).
// Q/K use transposed mfma(W,A) -> packed u2 stores; V uses mfma(A,W) + k-slot perm u2.
__global__ __launch_bounds__(256) void qkv_scan(
    const short* __restrict__ hp, const short* __restrict__ hv,
    const short* __restrict__ Wf, const float* __restrict__ bqs,
    const float* __restrict__ bk, const float* __restrict__ bv,
    const float* __restrict__ mask, int* __restrict__ flag,
    short* __restrict__ Q, short* __restrict__ K, short* __restrict__ Vt)
{
    const int bid = blockIdx.x;
    if (bid >= 256) {
        const u4* p = (const u4*)mask + (size_t)(bid - 256) * 4096 + threadIdx.x;
        u4 v[16];
#pragma unroll
        for (int k = 0; k < 16; k++) v[k] = p[(size_t)k * 256];
        const unsigned M = 0x7fffffffu;   // sign-masked: -0.0 counts as zero
        u4 o = (v[0] & M) | (v[1] & M);
#pragma unroll
        for (int k = 2; k < 16; k++) o |= (v[k] & M);
        unsigned a = (o[0] | o[1]) | (o[2] | o[3]);
        if (a != 0u) atomicOr(flag, 1);
        return;
    }
    __shared__ __align__(16) char lds[32768];   // hp tile 16KB + hv tile 16KB (XOR-swz)
    const int tid = threadIdx.x;
    const int w = tid >> 6, lane = tid & 63;
    const int lg = lane >> 4, lr = lane & 15;
    const int m0 = bid * 32;
    const int b = m0 >> 11, s0 = m0 & 2047;

    const char* hpg = (const char*)(hp + (size_t)m0 * 256);
    const char* hvg = (const char*)(hv + (size_t)m0 * 256);
#pragma unroll
    for (int i = 0; i < 4; i++) {
        const int L = i * 4096 + tid * 16;
        const int Ls = L ^ (((L >> 9) & 7) << 4);   // pre-swizzled source (rule 21)
        gload16(hpg + Ls, lds + L);
        gload16(hvg + Ls, lds + 16384 + L);
    }
    asm volatile("s_waitcnt vmcnt(0)" ::: "memory");
    __builtin_amdgcn_s_barrier();

#pragma unroll
    for (int ky = 0; ky < 3; ky++) {
        const char* Al = lds + (ky < 2 ? 0 : 16384);
        const short* Wb = Wf + ky * 65536 + (w * 4) * 512 + lane * 8;
#pragma unroll
        for (int half = 0; half < 2; half++) {
            f4 acc[4];
#pragma unroll
            for (int t = 0; t < 4; t++) acc[t] = (f4){0.f, 0.f, 0.f, 0.f};
#pragma unroll
            for (int k0g = 0; k0g < 8; k0g++) {
                bh8 af = *(const bh8*)(Al +
                    ((((half * 16 + lr) * 512) + k0g * 64 + lg * 16) ^ ((lr & 7) << 4)));
#pragma unroll
                for (int nt = 0; nt < 4; nt++) {
                    bh8 bf = *(const bh8*)(Wb + k0g * 8192 + nt * 512);
                    if (ky < 2)
                        acc[nt] = __builtin_amdgcn_mfma_f32_16x16x32_bf16(bf, af, acc[nt], 0, 0, 0);
                    else
                        acc[nt] = __builtin_amdgcn_mfma_f32_16x16x32_bf16(af, bf, acc[nt], 0, 0, 0);
                }
            }
            if (ky < 2) {
                // transposed: lane holds Q[s = s0+half*16+lr][n = w*64+nt*16+lg*4 + 0..3]
                short* P = (ky == 0) ? Q : K;
                const float* bb = (ky == 0) ? bqs : bk;
                const int s = s0 + half * 16 + lr;
#pragma unroll
                for (int nt = 0; nt < 4; nt++) {
                    const int nb = w * 64 + nt * 16 + lg * 4;
                    const int h = nb >> 5, hd = nb & 31;
                    f4 bias = *(const f4*)(bb + nb);
                    u2 o = { cvtpk(acc[nt][0] + bias[0], acc[nt][1] + bias[1]),
                             cvtpk(acc[nt][2] + bias[2], acc[nt][3] + bias[3]) };
                    *(u2*)(P + ((size_t)(b * Hh + h) * Ssz + s) * HDd + hd) = o;
                }
            } else {
                // normal: lane holds V[s = s0+half*16+lg*4 + 0..3][n = w*64+nt*16+lr]
                // k-slot perm: ps = lg*8 + half*4 + r  (consecutive in r -> packed u2)
#pragma unroll
                for (int nt = 0; nt < 4; nt++) {
                    const int n = w * 64 + nt * 16 + lr;
                    const int h = n >> 5, hd = n & 31;
                    const float bias = bv[n];
                    u2 o = { cvtpk(acc[nt][0] + bias, acc[nt][1] + bias),
                             cvtpk(acc[nt][2] + bias, acc[nt][3] + bias) };
                    *(u2*)(Vt + ((size_t)(b * Hh + h) * HDd + hd) * Ssz
                               + s0 + lg * 8 + half * 4) = o;
                }
            }
        }
    }
}

// ---------------- flash attention: 8 waves, 3-buffer LDS, 1 barrier/tile ----------------
// grid (S/128, B*H, NS), 512 thr. Waves 0-3 stage K, 4-7 stage V (1 gload16/thread/tile).
// P = exp2(S-8) static offset; denominator via ones-MFMA on the matrix pipe.
template<int NS>
__global__ __launch_bounds__(512) void attn(
    const short* __restrict__ Q, const short* __restrict__ Kb,
    const short* __restrict__ Vt, const float* __restrict__ mask,
    const int* __restrict__ flag, short* __restrict__ ctx,
    short* __restrict__ pacc, float* __restrict__ sums)
{
    __shared__ __align__(16) char lds[24576];    // 3 buffers x (K 4KB + V 4KB)
    const int tid = threadIdx.x;
    const int bh = blockIdx.y, b = bh >> 3, h = bh & 7;
    const int w = tid >> 6, lane = tid & 63;
    const int lg = lane >> 4, lr = lane & 15;
    const int q0 = blockIdx.x * 128 + w * 16;
    const int kz0 = blockIdx.z * (Ssz / NS);
    constexpr int NT = Ssz / NS / 64;

    const char* Kg = (const char*)(Kb + (size_t)bh * Ssz * HDd);
    const char* Vg = (const char*)(Vt + (size_t)bh * HDd * Ssz);
    const bool um = (*flag) != 0;
    const float* mrow = mask + ((size_t)b * Ssz + q0 + lr) * Ssz;

    // per-thread staging role: waves 0-3 -> K (4KB), waves 4-7 -> V (4KB)
    const char* sgp;      // per-lane global src for tile 0 (pre-swizzled, rule 21)
    size_t sstep;         // per-tile byte advance
    int ldo;              // wave-uniform LDS offset within buffer
    if (w < 4) {
        const int kt = w * 64 + lane;
        const int kx = (kt * 16) ^ (((kt >> 3) & 3) << 4);
        sgp = Kg + (size_t)kz0 * 64 + kx;
        sstep = 4096;
        ldo = w * 1024;
    } else {
        const int vt2 = (w - 4) * 64 + lane;
        const int vrow = vt2 >> 3;
        const int vcol = ((vt2 & 7) * 16) ^ ((vrow & 7) << 4);
        sgp = Vg + (size_t)vrow * (Ssz * 2) + (size_t)kz0 * 2 + vcol;
        sstep = 128;
        ldo = 4096 + (w - 4) * 1024;
    }

    // swizzled read offsets (within a buffer)
    const int koff  = (lr * 64 + lg * 16) ^ (((lr >> 1) & 3) << 4);
    const int voff0 = 4096 + ((lr * 128 + lg * 16) ^ ((lr & 7) << 4));
    const int voff1 = voff0 ^ 64;

    bh8 qf = *(const bh8*)(Q + ((size_t)bh * Ssz + q0 + lr) * HDd + lg * 8);
    const f4 c8 = {-8.f, -8.f, -8.f, -8.f};
    f4 acc0 = {0.f, 0.f, 0.f, 0.f}, acc1 = {0.f, 0.f, 0.f, 0.f};
    f4 sm = {0.f, 0.f, 0.f, 0.f};            // denominator accumulator (ones-MFMA)
    union { unsigned u[4]; bh8 v; } ones;
#pragma unroll
    for (int j = 0; j < 4; j++) ones.u[j] = 0x3F803F80u;

    auto stage = [&](int t, int buf) {
        gload16(sgp + (size_t)t * sstep, lds + buf * 8192 + ldo);
    };

    auto compute = [&](int t, int bs) {
        const char* kp = lds + bs + koff;
        bh8 k0 = *(const bh8*)(kp);
        bh8 k1 = *(const bh8*)(kp + 1024);
        bh8 k2 = *(const bh8*)(kp + 2048);
        bh8 k3 = *(const bh8*)(kp + 3072);
        const char* vp = lds + bs;
        bh8 v00 = *(const bh8*)(vp + voff0);
        bh8 v01 = *(const bh8*)(vp + voff1);
        bh8 v10 = *(const bh8*)(vp + voff0 + 2048);
        bh8 v11 = *(const bh8*)(vp + voff1 + 2048);

        // scores - 8 (log2 domain): D[key][q] + C, q = lr
        __builtin_amdgcn_s_setprio(1);
        f4 s0 = __builtin_amdgcn_mfma_f32_16x16x32_bf16(k0, qf, c8, 0, 0, 0);
        f4 s1 = __builtin_amdgcn_mfma_f32_16x16x32_bf16(k1, qf, c8, 0, 0, 0);
        f4 s2 = __builtin_amdgcn_mfma_f32_16x16x32_bf16(k2, qf, c8, 0, 0, 0);
        f4 s3 = __builtin_amdgcn_mfma_f32_16x16x32_bf16(k3, qf, c8, 0, 0, 0);
        __builtin_amdgcn_s_setprio(0);
        if (um) {
            const int kb = kz0 + t * 64;
            f4 m0v = *(const f4*)(mrow + kb + lg * 4);
            f4 m1v = *(const f4*)(mrow + kb + 16 + lg * 4);
            f4 m2v = *(const f4*)(mrow + kb + 32 + lg * 4);
            f4 m3v = *(const f4*)(mrow + kb + 48 + lg * 4);
            s0 += m0v * LOG2E; s1 += m1v * LOG2E; s2 += m2v * LOG2E; s3 += m3v * LOG2E;
        }

        // P = exp2(S - 8)
        float p[16];
#pragma unroll
        for (int j = 0; j < 4; j++) {
            p[j]      = fexp2(s0[j]);
            p[4 + j]  = fexp2(s1[j]);
            p[8 + j]  = fexp2(s2[j]);
            p[12 + j] = fexp2(s3[j]);
        }
        union { unsigned u[4]; bh8 v; } pf0, pf1;
        pf0.u[0] = cvtpk(p[0], p[1]);   pf0.u[1] = cvtpk(p[2], p[3]);
        pf0.u[2] = cvtpk(p[4], p[5]);   pf0.u[3] = cvtpk(p[6], p[7]);
        pf1.u[0] = cvtpk(p[8], p[9]);   pf1.u[1] = cvtpk(p[10], p[11]);
        pf1.u[2] = cvtpk(p[12], p[13]); pf1.u[3] = cvtpk(p[14], p[15]);

        __builtin_amdgcn_s_setprio(1);
        acc0 = __builtin_amdgcn_mfma_f32_16x16x32_bf16(v00, pf0.v, acc0, 0, 0, 0);
        acc0 = __builtin_amdgcn_mfma_f32_16x16x32_bf16(v01, pf1.v, acc0, 0, 0, 0);
        acc1 = __builtin_amdgcn_mfma_f32_16x16x32_bf16(v10, pf0.v, acc1, 0, 0, 0);
        acc1 = __builtin_amdgcn_mfma_f32_16x16x32_bf16(v11, pf1.v, acc1, 0, 0, 0);
        sm   = __builtin_amdgcn_mfma_f32_16x16x32_bf16(ones.v, pf0.v, sm, 0, 0, 0);
        sm   = __builtin_amdgcn_mfma_f32_16x16x32_bf16(ones.v, pf1.v, sm, 0, 0, 0);
        __builtin_amdgcn_s_setprio(0);
    };

    // prologue: two tiles in flight
    stage(0, 0);
    stage(1, 1);
    for (int t = 0; t < NT - 1; ++t) {
        asm volatile("s_waitcnt vmcnt(1)" ::: "memory");   // my stage(t) landed
        __builtin_amdgcn_s_barrier();                       // everyone's landed
        if (t + 2 < NT) stage(t + 2, (t + 2) % 3);          // buf[(t+2)%3] freed by compute(t-1)
        compute(t, (t % 3) * 8192);
    }
    asm volatile("s_waitcnt vmcnt(0)" ::: "memory");
    __builtin_amdgcn_s_barrier();
    compute(NT - 1, ((NT - 1) % 3) * 8192);

    const float sum = sm[0];   // D[row][q=lr] identical for all rows

    if constexpr (NS == 1) {
        float inv = 1.f / sum;
        short* cp = ctx + ((size_t)(b * Ssz + q0 + lr)) * Dsz + h * HDd + lg * 4;
#pragma unroll
        for (int r = 0; r < 4; r++) {
            cp[r]      = f2bf(acc0[r] * inv);
            cp[16 + r] = f2bf(acc1[r] * inv);
        }
    } else {
        // raw (unnormalized) partials; equal static offsets -> combine is a simple sum
        const size_t rbase = ((size_t)blockIdx.z * (Bsz * Hh) + bh) * Ssz + q0 + lr;
        short* pa = pacc + rbase * HDd;
        *(u2*)(pa + lg * 4)      = (u2){cvtpk(acc0[0], acc0[1]), cvtpk(acc0[2], acc0[3])};
        *(u2*)(pa + 16 + lg * 4) = (u2){cvtpk(acc1[0], acc1[1]), cvtpk(acc1[2], acc1[3])};
        if (lg == 0) sums[rbase] = sum;
    }
}

// ---------------- output projection; SPLIT=1 fuses the split-KV combine ----------------
// block = 16-row tile, wave = 64-col quarter; transposed mfma -> f4 coalesced stores.
template<int SPLIT>
__global__ __launch_bounds__(256) void out_gemm(
    const short* __restrict__ ctx, const short* __restrict__ pacc,
    const float* __restrict__ sums, const short* __restrict__ WfO,
    const float* __restrict__ bo, float* __restrict__ out)
{
    const int w = threadIdx.x >> 6, lane = threadIdx.x & 63;
    const int lg = lane >> 4, lr = lane & 15;
    const int m0 = blockIdx.x * 16;
    const int row = m0 + lr;                 // global (b,q) row
    const int b = row >> 11, q = row & 2047;
    f4 acc[4];
#pragma unroll
    for (int t = 0; t < 4; t++) acc[t] = (f4){0.f, 0.f, 0.f, 0.f};
    const short* ap = ctx + (size_t)row * 256 + lg * 8;
    const short* Wb = WfO + (w * 4) * 512 + lane * 8;
    constexpr size_t R = (size_t)(Bsz * Hh) * Ssz;   // rows per split half
#pragma unroll
    for (int k0g = 0; k0g < 8; k0g++) {
        union { unsigned u[4]; bh8 v; } af;
        if constexpr (SPLIT) {
            const int h = k0g;
            const size_t pr = ((size_t)(b * Hh + h)) * Ssz + q;
            const float inv = 1.f / (sums[pr] + sums[R + pr]);
            bh8 x0 = *(const bh8*)(pacc + pr * HDd + lg * 8);
            bh8 x1 = *(const bh8*)(pacc + (R + pr) * HDd + lg * 8);
            af.u[0] = cvtpk((bf2f(x0[0]) + bf2f(x1[0])) * inv, (bf2f(x0[1]) + bf2f(x1[1])) * inv);
            af.u[1] = cvtpk((bf2f(x0[2]) + bf2f(x1[2])) * inv, (bf2f(x0[3]) + bf2f(x1[3])) * inv);
            af.u[2] = cvtpk((bf2f(x0[4]) + bf2f(x1[4])) * inv, (bf2f(x0[5]) + bf2f(x1[5])) * inv);
            af.u[3] = cvtpk((bf2f(x0[6]) + bf2f(x1[6])) * inv, (bf2f(x0[7]) + bf2f(x1[7])) * inv);
        } else {
            af.v = *(const bh8*)(ap + k0g * 32);
        }
#pragma unroll
        for (int nt = 0; nt < 4; nt++) {
            bh8 bf = *(const bh8*)(Wb + k0g * 8192 + nt * 512);
            acc[nt] = __builtin_amdgcn_mfma_f32_16x16x32_bf16(bf, af.v, acc[nt], 0, 0, 0);
        }
    }
    // transposed C: lane holds out[row = m0+lr][n = w*64+nt*16+lg*4 + 0..3] -> f4 store
#pragma unroll
    for (int nt = 0; nt < 4; nt++) {
        const int nb = w * 64 + nt * 16 + lg * 4;
        f4 bias = *(const f4*)(bo + nb);
        f4 res = acc[nt] + bias;
        *(f4*)(out + (size_t)row * 256 + nb) = res;
    }
}

extern "C" void kernel_launch(void* const* d_in, const int* in_sizes, int n_in,
                              void* d_out, int out_size, void* d_ws, size_t ws_size,
                              hipStream_t stream)
{
    const float* hid  = (const float*)d_in[0];
    const float* pos  = (const float*)d_in[1];
    const float* mask = (const float*)d_in[2];
    const float* Wq   = (const float*)d_in[3];
    const float* bq   = (const float*)d_in[4];
    const float* Wk   = (const float*)d_in[5];
    const float* bk   = (const float*)d_in[6];
    const float* Wv   = (const float*)d_in[7];
    const float* bv   = (const float*)d_in[8];
    const float* Wo   = (const float*)d_in[9];
    const float* bo   = (const float*)d_in[10];
    float* out = (float*)d_out;

    char* ws = (char*)d_ws;
    short* Wf   = (short*)(ws);                    // 512 KB fragment-packed weights
    float* bqs  = (float*)(ws + (512 << 10));      // 1 KB
    int*   flag = (int*)  (ws + (516 << 10));      // 4 B
    short* hp   = (short*)(ws + (1  << 20));       // 4 MB  bf16(hid+pos)
    short* hv   = (short*)(ws + (5  << 20));       // 4 MB  bf16(hid)
    short* Qb   = (short*)(ws + (9  << 20));       // 4 MB  [B,H,S,32]
    short* Kb   = (short*)(ws + (13 << 20));       // 4 MB  [B,H,S,32]
    short* Vtb  = (short*)(ws + (17 << 20));       // 4 MB  [B,H,32,S] (k-slot permuted)
    short* ctxb = (short*)(ws + (21 << 20));       // 4 MB  [B,S,256] (NS=1 path only)
    short* pacc = (short*)(ws + (25 << 20));       // 8.4 MB [2,B*H,S,32] raw partials
    float* sums = (float*)(ws + (34 << 20));       // 512 KB [2,B*H,S]

    prep_fast<<<1280, 256, 0, stream>>>(hid, pos, Wq, Wk, Wv, Wo, bq, Wf, bqs, hp, hv, flag);
    qkv_scan<<<1280, 256, 0, stream>>>(hp, hv, Wf, bqs, bk, bv, mask, flag, Qb, Kb, Vtb);

    const bool split = ws_size >= ((size_t)36 << 20);
    if (split) {
        attn<2><<<dim3(16, 32, 2), 512, 0, stream>>>(Qb, Kb, Vtb, mask, flag, ctxb, pacc, sums);
        out_gemm<1><<<512, 256, 0, stream>>>(ctxb, pacc, sums, Wf + 196608, bo, out);
    } else {
        attn<1><<<dim3(16, 32, 1), 512, 0, stream>>>(Qb, Kb, Vtb, mask, flag, ctxb, pacc, sums);
        out_gemm<0><<<512, 256, 0, stream>>>(ctxb, pacc, sums, Wf + 196608, bo, out);
    }
}

// Round 15
// 65.911 us; speedup vs baseline: 1.4603x; 1.4603x over previous
//
#include <hip/hip_runtime.h>
#include <hip/hip_bf16.h>

#define Bsz 4
#define Ssz 2048
#define Dsz 256
#define Hh 8
#define HDd 32

typedef __attribute__((ext_vector_type(8))) short bh8;
typedef __attribute__((ext_vector_type(4))) float f4;
typedef __attribute__((ext_vector_type(4))) unsigned u4;
typedef __attribute__((ext_vector_type(2))) unsigned u2;

#define SCAL 0.17677669529663687f   /* 32^-0.5 */
#define LOG2E 1.4426950408889634f
#define QSCALE (SCAL * LOG2E)

__device__ __forceinline__ short f2bf(float f) {
    union { float f; unsigned u; } x; x.f = f;
    unsigned r = x.u + 0x7fffu + ((x.u >> 16) & 1u);
    return (short)(r >> 16);
}

__device__ __forceinline__ float bf2f(short s) {
    union { unsigned u; float f; } x;
    x.u = ((unsigned)(unsigned short)s) << 16;
    return x.f;
}

__device__ __forceinline__ float fexp2(float x) {
#if __has_builtin(__builtin_amdgcn_exp2f)
    return __builtin_amdgcn_exp2f(x);
#else
    float r; asm("v_exp_f32 %0, %1" : "=v"(r) : "v"(x)); return r;
#endif
}

__device__ __forceinline__ unsigned cvtpk(float lo, float hi) {
    unsigned r; asm("v_cvt_pk_bf16_f32 %0, %1, %2" : "=v"(r) : "v"(lo), "v"(hi));
    return r;
}

__device__ __forceinline__ void gload16(const void* g, void* l) {
    __builtin_amdgcn_global_load_lds(
        (const __attribute__((address_space(1))) unsigned int*)g,
        (__attribute__((address_space(3))) unsigned int*)l, 16, 0, 0);
}

// ---------------- prep: fragment-packed weights + hp/hv bf16 + flag zero ----------------
// Wf layout per matrix (65536 shorts): [k0g=d>>5][ntile=n>>4][lane=((d>>3)&3)*16+(n&15)][j=d&7]
__global__ __launch_bounds__(256) void prep_fast(
    const float* __restrict__ hid, const float* __restrict__ pos,
    const float* __restrict__ Wq, const float* __restrict__ Wk,
    const float* __restrict__ Wv, const float* __restrict__ Wo,
    const float* __restrict__ bq,
    short* __restrict__ Wf, float* __restrict__ bqs,
    short* __restrict__ hp, short* __restrict__ hv,
    int* __restrict__ flag)
{
    const int bid = blockIdx.x;
    if (bid < 256) {
        int t = bid * 256 + threadIdx.x;   // t = d*256 + n
        int d = t >> 8, n = t & 255;
        int off = (((d >> 5) * 16 + (n >> 4)) * 64 + ((d >> 3) & 3) * 16 + (n & 15)) * 8 + (d & 7);
        Wf[off]          = f2bf(Wq[t] * QSCALE);
        Wf[65536 + off]  = f2bf(Wk[t]);
        Wf[131072 + off] = f2bf(Wv[t]);
        Wf[196608 + off] = f2bf(Wo[t]);
        if (t == 0) *flag = 0;
        if (t < 256) bqs[t] = bq[t] * QSCALE;
    } else {
        const size_t i = ((size_t)(bid - 256) * 256 + threadIdx.x) * 8;
        f4 h1 = *(const f4*)(hid + i), h2 = *(const f4*)(hid + i + 4);
        f4 p1 = *(const f4*)(pos + i), p2 = *(const f4*)(pos + i + 4);
        union { unsigned u[4]; bh8 v; } a, b;
        a.u[0] = cvtpk(h1[0] + p1[0], h1[1] + p1[1]);
        a.u[1] = cvtpk(h1[2] + p1[2], h1[3] + p1[3]);
        a.u[2] = cvtpk(h2[0] + p2[0], h2[1] + p2[1]);
        a.u[3] = cvtpk(h2[2] + p2[2], h2[3] + p2[3]);
        b.u[0] = cvtpk(h1[0], h1[1]); b.u[1] = cvtpk(h1[2], h1[3]);
        b.u[2] = cvtpk(h2[0], h2[1]); b.u[3] = cvtpk(h2[2], h2[3]);
        *(bh8*)(hp + i) = a.v;
        *(bh8*)(hv + i) = b.v;
    }
}

// ---------------- fused QKV projection + mask scan ----------------
// blocks [0,512): gemm, 16 rows/block (512*16 = B*S = 8192), fragment-packed LDS A-tile;
// blocks [512,1536): mask scan (lane-contiguous, 16 independent 1KB-coalesced loads).
// Q/K use transposed mfma(W,A) -> packed u2 stores; V uses mfma(A,W) + k-slot perm u2.
__global__ __launch_bounds__(256) void qkv_scan(
    const short* __restrict__ hp, const short* __restrict__ hv,
    const short* __restrict__ Wf, const float* __restrict__ bqs,
    const float* __restrict__ bk, const float* __restrict__ bv,
    const float* __restrict__ mask, int* __restrict__ flag,
    short* __restrict__ Q, short* __restrict__ K, short* __restrict__ Vt)
{
    const int bid = blockIdx.x;
    if (bid >= 512) {
        const u4* p = (const u4*)mask + (size_t)(bid - 512) * 4096 + threadIdx.x;
        u4 v[16];
#pragma unroll
        for (int k = 0; k < 16; k++) v[k] = p[(size_t)k * 256];
        const unsigned M = 0x7fffffffu;   // sign-masked: -0.0 counts as zero
        u4 o = (v[0] & M) | (v[1] & M);
#pragma unroll
        for (int k = 2; k < 16; k++) o |= (v[k] & M);
        unsigned a = (o[0] | o[1]) | (o[2] | o[3]);
        if (a != 0u) atomicOr(flag, 1);
        return;
    }
    __shared__ __align__(16) char lds[16384];   // 2 matrices x [k0g][lane][16B] (8KB each)
    const int tid = threadIdx.x;
    const int w = tid >> 6, lane = tid & 63;
    const int lg = lane >> 4, lr = lane & 15;
    const int m0 = bid * 16;                    // 16 rows/block
    const int b = m0 >> 11, s0 = m0 & 2047;

    // fragment-packed staging: LDS[mat][k0g][lane][16B]; global src carries the
    // permutation (per-lane), LDS dest is wave-uniform + lane*16 (gload_lds rule).
    // round-trip: lds[k0g*1024 + L*16] = A[(L&15) row][k0g*32 + (L>>4)*8 .. +8]
    const char* hpg = (const char*)(hp + (size_t)m0 * 256);
    const char* hvg = (const char*)(hv + (size_t)m0 * 256);
    const int rsub = lr * 512 + lg * 16;
#pragma unroll
    for (int i = 0; i < 2; i++) {
        const int k0g = i * 4 + w;              // 8 chunks over 2 wave-rounds
        const int src = k0g * 64 + rsub;
        const int dst = k0g * 1024;             // + lane*16 by hardware
        gload16(hpg + src, lds + dst);
        gload16(hvg + src, lds + 8192 + dst);
    }
    asm volatile("s_waitcnt vmcnt(0)" ::: "memory");
    __builtin_amdgcn_s_barrier();

    const int vhalf = (s0 >> 4) & 1;            // position within 32-key perm block
#pragma unroll
    for (int ky = 0; ky < 3; ky++) {
        const char* Al = lds + (ky < 2 ? 0 : 8192);
        const short* Wb = Wf + ky * 65536 + (w * 4) * 512 + lane * 8;
        f4 acc[4];
#pragma unroll
        for (int t = 0; t < 4; t++) acc[t] = (f4){0.f, 0.f, 0.f, 0.f};
#pragma unroll
        for (int k0g = 0; k0g < 8; k0g++) {
            bh8 af  = *(const bh8*)(Al + k0g * 1024 + lane * 16);
            bh8 bf0 = *(const bh8*)(Wb + k0g * 8192);
            bh8 bf1 = *(const bh8*)(Wb + k0g * 8192 + 512);
            bh8 bf2 = *(const bh8*)(Wb + k0g * 8192 + 1024);
            bh8 bf3 = *(const bh8*)(Wb + k0g * 8192 + 1536);
            if (ky < 2) {
                acc[0] = __builtin_amdgcn_mfma_f32_16x16x32_bf16(bf0, af, acc[0], 0, 0, 0);
                acc[1] = __builtin_amdgcn_mfma_f32_16x16x32_bf16(bf1, af, acc[1], 0, 0, 0);
                acc[2] = __builtin_amdgcn_mfma_f32_16x16x32_bf16(bf2, af, acc[2], 0, 0, 0);
                acc[3] = __builtin_amdgcn_mfma_f32_16x16x32_bf16(bf3, af, acc[3], 0, 0, 0);
            } else {
                acc[0] = __builtin_amdgcn_mfma_f32_16x16x32_bf16(af, bf0, acc[0], 0, 0, 0);
                acc[1] = __builtin_amdgcn_mfma_f32_16x16x32_bf16(af, bf1, acc[1], 0, 0, 0);
                acc[2] = __builtin_amdgcn_mfma_f32_16x16x32_bf16(af, bf2, acc[2], 0, 0, 0);
                acc[3] = __builtin_amdgcn_mfma_f32_16x16x32_bf16(af, bf3, acc[3], 0, 0, 0);
            }
        }
        if (ky < 2) {
            // transposed: lane holds P[s = s0+lr][n = w*64+nt*16+lg*4 + 0..3]
            short* P = (ky == 0) ? Q : K;
            const float* bb = (ky == 0) ? bqs : bk;
            const int s = s0 + lr;
#pragma unroll
            for (int nt = 0; nt < 4; nt++) {
                const int nb = w * 64 + nt * 16 + lg * 4;
                const int h = nb >> 5, hd = nb & 31;
                f4 bias = *(const f4*)(bb + nb);
                u2 o = { cvtpk(acc[nt][0] + bias[0], acc[nt][1] + bias[1]),
                         cvtpk(acc[nt][2] + bias[2], acc[nt][3] + bias[3]) };
                *(u2*)(P + ((size_t)(b * Hh + h) * Ssz + s) * HDd + hd) = o;
            }
        } else {
            // normal: lane holds V[s = s0+lg*4 + 0..3][n = w*64+nt*16+lr]
            // k-slot perm within 32-key block: ps = lg*8 + vhalf*4 + r (consecutive in r)
#pragma unroll
            for (int nt = 0; nt < 4; nt++) {
                const int n = w * 64 + nt * 16 + lr;
                const int h = n >> 5, hd = n & 31;
                const float bias = bv[n];
                u2 o = { cvtpk(acc[nt][0] + bias, acc[nt][1] + bias),
                         cvtpk(acc[nt][2] + bias, acc[nt][3] + bias) };
                *(u2*)(Vt + ((size_t)(b * Hh + h) * HDd + hd) * Ssz
                           + (s0 & ~31) + lg * 8 + vhalf * 4) = o;
            }
        }
    }
}

// ---------------- flash attention: 8 waves, 3-buffer LDS, 1 barrier/tile ----------------
// grid (S/128, B*H, NS), 512 thr. Waves 0-3 stage K, 4-7 stage V (1 gload16/thread/tile).
// P = exp2(S-8) static offset; denominator via ones-MFMA on the matrix pipe.
template<int NS>
__global__ __launch_bounds__(512) void attn(
    const short* __restrict__ Q, const short* __restrict__ Kb,
    const short* __restrict__ Vt, const float* __restrict__ mask,
    const int* __restrict__ flag, short* __restrict__ ctx,
    short* __restrict__ pacc, float* __restrict__ sums)
{
    __shared__ __align__(16) char lds[24576];    // 3 buffers x (K 4KB + V 4KB)
    const int tid = threadIdx.x;
    const int bh = blockIdx.y, b = bh >> 3, h = bh & 7;
    const int w = tid >> 6, lane = tid & 63;
    const int lg = lane >> 4, lr = lane & 15;
    const int q0 = blockIdx.x * 128 + w * 16;
    const int kz0 = blockIdx.z * (Ssz / NS);
    constexpr int NT = Ssz / NS / 64;

    const char* Kg = (const char*)(Kb + (size_t)bh * Ssz * HDd);
    const char* Vg = (const char*)(Vt + (size_t)bh * HDd * Ssz);
    const bool um = (*flag) != 0;
    const float* mrow = mask + ((size_t)b * Ssz + q0 + lr) * Ssz;

    // per-thread staging role: waves 0-3 -> K (4KB), waves 4-7 -> V (4KB)
    const char* sgp;      // per-lane global src for tile 0 (pre-swizzled, rule 21)
    size_t sstep;         // per-tile byte advance
    int ldo;              // wave-uniform LDS offset within buffer
    if (w < 4) {
        const int kt = w * 64 + lane;
        const int kx = (kt * 16) ^ (((kt >> 3) & 3) << 4);
        sgp = Kg + (size_t)kz0 * 64 + kx;
        sstep = 4096;
        ldo = w * 1024;
    } else {
        const int vt2 = (w - 4) * 64 + lane;
        const int vrow = vt2 >> 3;
        const int vcol = ((vt2 & 7) * 16) ^ ((vrow & 7) << 4);
        sgp = Vg + (size_t)vrow * (Ssz * 2) + (size_t)kz0 * 2 + vcol;
        sstep = 128;
        ldo = 4096 + (w - 4) * 1024;
    }

    // swizzled read offsets (within a buffer)
    const int koff  = (lr * 64 + lg * 16) ^ (((lr >> 1) & 3) << 4);
    const int voff0 = 4096 + ((lr * 128 + lg * 16) ^ ((lr & 7) << 4));
    const int voff1 = voff0 ^ 64;

    bh8 qf = *(const bh8*)(Q + ((size_t)bh * Ssz + q0 + lr) * HDd + lg * 8);
    const f4 c8 = {-8.f, -8.f, -8.f, -8.f};
    f4 acc0 = {0.f, 0.f, 0.f, 0.f}, acc1 = {0.f, 0.f, 0.f, 0.f};
    f4 sm = {0.f, 0.f, 0.f, 0.f};            // denominator accumulator (ones-MFMA)
    union { unsigned u[4]; bh8 v; } ones;
#pragma unroll
    for (int j = 0; j < 4; j++) ones.u[j] = 0x3F803F80u;

    auto stage = [&](int t, int buf) {
        gload16(sgp + (size_t)t * sstep, lds + buf * 8192 + ldo);
    };

    auto compute = [&](int t, int bs) {
        const char* kp = lds + bs + koff;
        bh8 k0 = *(const bh8*)(kp);
        bh8 k1 = *(const bh8*)(kp + 1024);
        bh8 k2 = *(const bh8*)(kp + 2048);
        bh8 k3 = *(const bh8*)(kp + 3072);
        const char* vp = lds + bs;
        bh8 v00 = *(const bh8*)(vp + voff0);
        bh8 v01 = *(const bh8*)(vp + voff1);
        bh8 v10 = *(const bh8*)(vp + voff0 + 2048);
        bh8 v11 = *(const bh8*)(vp + voff1 + 2048);

        // scores - 8 (log2 domain): D[key][q] + C, q = lr
        __builtin_amdgcn_s_setprio(1);
        f4 s0 = __builtin_amdgcn_mfma_f32_16x16x32_bf16(k0, qf, c8, 0, 0, 0);
        f4 s1 = __builtin_amdgcn_mfma_f32_16x16x32_bf16(k1, qf, c8, 0, 0, 0);
        f4 s2 = __builtin_amdgcn_mfma_f32_16x16x32_bf16(k2, qf, c8, 0, 0, 0);
        f4 s3 = __builtin_amdgcn_mfma_f32_16x16x32_bf16(k3, qf, c8, 0, 0, 0);
        __builtin_amdgcn_s_setprio(0);
        if (um) {
            const int kb = kz0 + t * 64;
            f4 m0v = *(const f4*)(mrow + kb + lg * 4);
            f4 m1v = *(const f4*)(mrow + kb + 16 + lg * 4);
            f4 m2v = *(const f4*)(mrow + kb + 32 + lg * 4);
            f4 m3v = *(const f4*)(mrow + kb + 48 + lg * 4);
            s0 += m0v * LOG2E; s1 += m1v * LOG2E; s2 += m2v * LOG2E; s3 += m3v * LOG2E;
        }

        // P = exp2(S - 8)
        float p[16];
#pragma unroll
        for (int j = 0; j < 4; j++) {
            p[j]      = fexp2(s0[j]);
            p[4 + j]  = fexp2(s1[j]);
            p[8 + j]  = fexp2(s2[j]);
            p[12 + j] = fexp2(s3[j]);
        }
        union { unsigned u[4]; bh8 v; } pf0, pf1;
        pf0.u[0] = cvtpk(p[0], p[1]);   pf0.u[1] = cvtpk(p[2], p[3]);
        pf0.u[2] = cvtpk(p[4], p[5]);   pf0.u[3] = cvtpk(p[6], p[7]);
        pf1.u[0] = cvtpk(p[8], p[9]);   pf1.u[1] = cvtpk(p[10], p[11]);
        pf1.u[2] = cvtpk(p[12], p[13]); pf1.u[3] = cvtpk(p[14], p[15]);

        __builtin_amdgcn_s_setprio(1);
        acc0 = __builtin_amdgcn_mfma_f32_16x16x32_bf16(v00, pf0.v, acc0, 0, 0, 0);
        acc0 = __builtin_amdgcn_mfma_f32_16x16x32_bf16(v01, pf1.v, acc0, 0, 0, 0);
        acc1 = __builtin_amdgcn_mfma_f32_16x16x32_bf16(v10, pf0.v, acc1, 0, 0, 0);
        acc1 = __builtin_amdgcn_mfma_f32_16x16x32_bf16(v11, pf1.v, acc1, 0, 0, 0);
        sm   = __builtin_amdgcn_mfma_f32_16x16x32_bf16(ones.v, pf0.v, sm, 0, 0, 0);
        sm   = __builtin_amdgcn_mfma_f32_16x16x32_bf16(ones.v, pf1.v, sm, 0, 0, 0);
        __builtin_amdgcn_s_setprio(0);
    };

    // prologue: two tiles in flight
    stage(0, 0);
    stage(1, 1);
    for (int t = 0; t < NT - 1; ++t) {
        asm volatile("s_waitcnt vmcnt(1)" ::: "memory");   // my stage(t) landed
        __builtin_amdgcn_s_barrier();                       // everyone's landed
        if (t + 2 < NT) stage(t + 2, (t + 2) % 3);          // buf[(t+2)%3] freed by compute(t-1)
        compute(t, (t % 3) * 8192);
    }
    asm volatile("s_waitcnt vmcnt(0)" ::: "memory");
    __builtin_amdgcn_s_barrier();
    compute(NT - 1, ((NT - 1) % 3) * 8192);

    const float sum = sm[0];   // D[row][q=lr] identical for all rows

    if constexpr (NS == 1) {
        float inv = 1.f / sum;
        short* cp = ctx + ((size_t)(b * Ssz + q0 + lr)) * Dsz + h * HDd + lg * 4;
#pragma unroll
        for (int r = 0; r < 4; r++) {
            cp[r]      = f2bf(acc0[r] * inv);
            cp[16 + r] = f2bf(acc1[r] * inv);
        }
    } else {
        // raw (unnormalized) partials; equal static offsets -> combine is a simple sum
        const size_t rbase = ((size_t)blockIdx.z * (Bsz * Hh) + bh) * Ssz + q0 + lr;
        short* pa = pacc + rbase * HDd;
        *(u2*)(pa + lg * 4)      = (u2){cvtpk(acc0[0], acc0[1]), cvtpk(acc0[2], acc0[3])};
        *(u2*)(pa + 16 + lg * 4) = (u2){cvtpk(acc1[0], acc1[1]), cvtpk(acc1[2], acc1[3])};
        if (lg == 0) sums[rbase] = sum;
    }
}

// ---------------- output projection; SPLIT=1 fuses the split-KV combine ----------------
// block = 16-row tile, wave = 64-col quarter; transposed mfma -> f4 coalesced stores.
template<int SPLIT>
__global__ __launch_bounds__(256) void out_gemm(
    const short* __restrict__ ctx, const short* __restrict__ pacc,
    const float* __restrict__ sums, const short* __restrict__ WfO,
    const float* __restrict__ bo, float* __restrict__ out)
{
    const int w = threadIdx.x >> 6, lane = threadIdx.x & 63;
    const int lg = lane >> 4, lr = lane & 15;
    const int m0 = blockIdx.x * 16;
    const int row = m0 + lr;                 // global (b,q) row
    const int b = row >> 11, q = row & 2047;
    f4 acc[4];
#pragma unroll
    for (int t = 0; t < 4; t++) acc[t] = (f4){0.f, 0.f, 0.f, 0.f};
    const short* ap = ctx + (size_t)row * 256 + lg * 8;
    const short* Wb = WfO + (w * 4) * 512 + lane * 8;
    constexpr size_t R = (size_t)(Bsz * Hh) * Ssz;   // rows per split half
#pragma unroll
    for (int k0g = 0; k0g < 8; k0g++) {
        union { unsigned u[4]; bh8 v; } af;
        if constexpr (SPLIT) {
            const int h = k0g;
            const size_t pr = ((size_t)(b * Hh + h)) * Ssz + q;
            const float inv = 1.f / (sums[pr] + sums[R + pr]);
            bh8 x0 = *(const bh8*)(pacc + pr * HDd + lg * 8);
            bh8 x1 = *(const bh8*)(pacc + (R + pr) * HDd + lg * 8);
            af.u[0] = cvtpk((bf2f(x0[0]) + bf2f(x1[0])) * inv, (bf2f(x0[1]) + bf2f(x1[1])) * inv);
            af.u[1] = cvtpk((bf2f(x0[2]) + bf2f(x1[2])) * inv, (bf2f(x0[3]) + bf2f(x1[3])) * inv);
            af.u[2] = cvtpk((bf2f(x0[4]) + bf2f(x1[4])) * inv, (bf2f(x0[5]) + bf2f(x1[5])) * inv);
            af.u[3] = cvtpk((bf2f(x0[6]) + bf2f(x1[6])) * inv, (bf2f(x0[7]) + bf2f(x1[7])) * inv);
        } else {
            af.v = *(const bh8*)(ap + k0g * 32);
        }
#pragma unroll
        for (int nt = 0; nt < 4; nt++) {
            bh8 bf = *(const bh8*)(Wb + k0g * 8192 + nt * 512);
            acc[nt] = __builtin_amdgcn_mfma_f32_16x16x32_bf16(bf, af.v, acc[nt], 0, 0, 0);
        }
    }
    // transposed C: lane holds out[row = m0+lr][n = w*64+nt*16+lg*4 + 0..3] -> f4 store
#pragma unroll
    for (int nt = 0; nt < 4; nt++) {
        const int nb = w * 64 + nt * 16 + lg * 4;
        f4 bias = *(const f4*)(bo + nb);
        f4 res = acc[nt] + bias;
        *(f4*)(out + (size_t)row * 256 + nb) = res;
    }
}

extern "C" void kernel_launch(void* const* d_in, const int* in_sizes, int n_in,
                              void* d_out, int out_size, void* d_ws, size_t ws_size,
                              hipStream_t stream)
{
    const float* hid  = (const float*)d_in[0];
    const float* pos  = (const float*)d_in[1];
    const float* mask = (const float*)d_in[2];
    const float* Wq   = (const float*)d_in[3];
    const float* bq   = (const float*)d_in[4];
    const float* Wk   = (const float*)d_in[5];
    const float* bk   = (const float*)d_in[6];
    const float* Wv   = (const float*)d_in[7];
    const float* bv   = (const float*)d_in[8];
    const float* Wo   = (const float*)d_in[9];
    const float* bo   = (const float*)d_in[10];
    float* out = (float*)d_out;

    char* ws = (char*)d_ws;
    short* Wf   = (short*)(ws);                    // 512 KB fragment-packed weights
    float* bqs  = (float*)(ws + (512 << 10));      // 1 KB
    int*   flag = (int*)  (ws + (516 << 10));      // 4 B
    short* hp   = (short*)(ws + (1  << 20));       // 4 MB  bf16(hid+pos)
    short* hv   = (short*)(ws + (5  << 20));       // 4 MB  bf16(hid)
    short* Qb   = (short*)(ws + (9  << 20));       // 4 MB  [B,H,S,32]
    short* Kb   = (short*)(ws + (13 << 20));       // 4 MB  [B,H,S,32]
    short* Vtb  = (short*)(ws + (17 << 20));       // 4 MB  [B,H,32,S] (k-slot permuted)
    short* ctxb = (short*)(ws + (21 << 20));       // 4 MB  [B,S,256] (NS=1 path only)
    short* pacc = (short*)(ws + (25 << 20));       // 8.4 MB [2,B*H,S,32] raw partials
    float* sums = (float*)(ws + (34 << 20));       // 512 KB [2,B*H,S]

    prep_fast<<<1280, 256, 0, stream>>>(hid, pos, Wq, Wk, Wv, Wo, bq, Wf, bqs, hp, hv, flag);
    qkv_scan<<<1536, 256, 0, stream>>>(hp, hv, Wf, bqs, bk, bv, mask, flag, Qb, Kb, Vtb);

    const bool split = ws_size >= ((size_t)36 << 20);
    if (split) {
        attn<2><<<dim3(16, 32, 2), 512, 0, stream>>>(Qb, Kb, Vtb, mask, flag, ctxb, pacc, sums);
        out_gemm<1><<<512, 256, 0, stream>>>(ctxb, pacc, sums, Wf + 196608, bo, out);
    } else {
        attn<1><<<dim3(16, 32, 1), 512, 0, stream>>>(Qb, Kb, Vtb, mask, flag, ctxb, pacc, sums);
        out_gemm<0><<<512, 256, 0, stream>>>(ctxb, pacc, sums, Wf + 196608, bo, out);
    }
}

// Round 16
// 64.390 us; speedup vs baseline: 1.4948x; 1.0236x over previous
//
#include <hip/hip_runtime.h>
#include <hip/hip_bf16.h>

#define Bsz 4
#define Ssz 2048
#define Dsz 256
#define Hh 8
#define HDd 32

typedef __attribute__((ext_vector_type(8))) short bh8;
typedef __attribute__((ext_vector_type(4))) float f4;
typedef __attribute__((ext_vector_type(4))) unsigned u4;
typedef __attribute__((ext_vector_type(2))) unsigned u2;

#define SCAL 0.17677669529663687f   /* 32^-0.5 */
#define LOG2E 1.4426950408889634f
#define QSCALE (SCAL * LOG2E)

__device__ __forceinline__ short f2bf(float f) {
    union { float f; unsigned u; } x; x.f = f;
    unsigned r = x.u + 0x7fffu + ((x.u >> 16) & 1u);
    return (short)(r >> 16);
}

__device__ __forceinline__ float bf2f(short s) {
    union { unsigned u; float f; } x;
    x.u = ((unsigned)(unsigned short)s) << 16;
    return x.f;
}

__device__ __forceinline__ float fexp2(float x) {
#if __has_builtin(__builtin_amdgcn_exp2f)
    return __builtin_amdgcn_exp2f(x);
#else
    float r; asm("v_exp_f32 %0, %1" : "=v"(r) : "v"(x)); return r;
#endif
}

__device__ __forceinline__ unsigned cvtpk(float lo, float hi) {
    unsigned r; asm("v_cvt_pk_bf16_f32 %0, %1, %2" : "=v"(r) : "v"(lo), "v"(hi));
    return r;
}

__device__ __forceinline__ void gload16(const void* g, void* l) {
    __builtin_amdgcn_global_load_lds(
        (const __attribute__((address_space(1))) unsigned int*)g,
        (__attribute__((address_space(3))) unsigned int*)l, 16, 0, 0);
}

// ---------------- prep: fragment-packed weights + flag zero (256 blocks) ----------------
// Wf layout per matrix (65536 shorts): [k0g=d>>5][ntile=n>>4][lane=((d>>3)&3)*16+(n&15)][j=d&7]
__global__ __launch_bounds__(256) void prep_fast(
    const float* __restrict__ Wq, const float* __restrict__ Wk,
    const float* __restrict__ Wv, const float* __restrict__ Wo,
    const float* __restrict__ bq,
    short* __restrict__ Wf, float* __restrict__ bqs,
    int* __restrict__ flag)
{
    int t = blockIdx.x * 256 + threadIdx.x;   // t = d*256 + n
    int d = t >> 8, n = t & 255;
    int off = (((d >> 5) * 16 + (n >> 4)) * 64 + ((d >> 3) & 3) * 16 + (n & 15)) * 8 + (d & 7);
    Wf[off]          = f2bf(Wq[t] * QSCALE);
    Wf[65536 + off]  = f2bf(Wk[t]);
    Wf[131072 + off] = f2bf(Wv[t]);
    Wf[196608 + off] = f2bf(Wo[t]);
    if (t == 0) *flag = 0;
    if (t < 256) bqs[t] = bq[t] * QSCALE;
}

// ---------------- fused QKV projection + mask scan ----------------
// blocks [0,512): gemm, 16 rows/block; reads hid/pos fp32 directly, converts in-register,
// ds_writes fragment-packed A tiles (hp at 0, hv at 8KB). blocks [512,1536): mask scan.
// Q/K use transposed mfma(W,A) -> packed u2 stores; V uses mfma(A,W) + k-slot perm u2.
__global__ __launch_bounds__(256) void qkv_scan(
    const float* __restrict__ hid, const float* __restrict__ pos,
    const short* __restrict__ Wf, const float* __restrict__ bqs,
    const float* __restrict__ bk, const float* __restrict__ bv,
    const float* __restrict__ mask, int* __restrict__ flag,
    short* __restrict__ Q, short* __restrict__ K, short* __restrict__ Vt)
{
    const int bid = blockIdx.x;
    if (bid >= 512) {
        const u4* p = (const u4*)mask + (size_t)(bid - 512) * 4096 + threadIdx.x;
        u4 v[16];
#pragma unroll
        for (int k = 0; k < 16; k++) v[k] = p[(size_t)k * 256];
        const unsigned M = 0x7fffffffu;   // sign-masked: -0.0 counts as zero
        u4 o = (v[0] & M) | (v[1] & M);
#pragma unroll
        for (int k = 2; k < 16; k++) o |= (v[k] & M);
        unsigned a = (o[0] | o[1]) | (o[2] | o[3]);
        if (a != 0u) atomicOr(flag, 1);
        return;
    }
    __shared__ __align__(16) char lds[16384];   // hp frag-packed 8KB + hv 8KB
    const int tid = threadIdx.x;
    const int w = tid >> 6, lane = tid & 63;
    const int lg = lane >> 4, lr = lane & 15;
    const int m0 = bid * 16;                    // 16 rows/block (512*16 = B*S)
    const int b = m0 >> 11, s0 = m0 & 2047;

    // ---- staging: row = tid>>4, chunk c = tid&15 -> 16 floats (2 slices: 2c, 2c+1) ----
    {
        const int row = tid >> 4, c = tid & 15;
        const float* hb = hid + (size_t)(m0 + row) * 256 + c * 16;
        const float* pb = pos + (size_t)(m0 + row) * 256 + c * 16;
        f4 h0 = *(const f4*)(hb), h1 = *(const f4*)(hb + 4);
        f4 h2 = *(const f4*)(hb + 8), h3 = *(const f4*)(hb + 12);
        f4 p0 = *(const f4*)(pb), p1 = *(const f4*)(pb + 4);
        f4 p2 = *(const f4*)(pb + 8), p3 = *(const f4*)(pb + 12);
        // slot for slice s: off = (s>>2)*1024 + (s&3)*256 + row*16 ; s = 2c (then +256 for 2c+1)
        const int off = ((c >> 1) * 1024) + (((2 * c) & 3) * 256) + row * 16;
        u4 hp0 = { cvtpk(h0[0] + p0[0], h0[1] + p0[1]), cvtpk(h0[2] + p0[2], h0[3] + p0[3]),
                   cvtpk(h1[0] + p1[0], h1[1] + p1[1]), cvtpk(h1[2] + p1[2], h1[3] + p1[3]) };
        u4 hp1 = { cvtpk(h2[0] + p2[0], h2[1] + p2[1]), cvtpk(h2[2] + p2[2], h2[3] + p2[3]),
                   cvtpk(h3[0] + p3[0], h3[1] + p3[1]), cvtpk(h3[2] + p3[2], h3[3] + p3[3]) };
        u4 hv0 = { cvtpk(h0[0], h0[1]), cvtpk(h0[2], h0[3]),
                   cvtpk(h1[0], h1[1]), cvtpk(h1[2], h1[3]) };
        u4 hv1 = { cvtpk(h2[0], h2[1]), cvtpk(h2[2], h2[3]),
                   cvtpk(h3[0], h3[1]), cvtpk(h3[2], h3[3]) };
        *(u4*)(lds + off)          = hp0;
        *(u4*)(lds + off + 256)    = hp1;
        *(u4*)(lds + 8192 + off)       = hv0;
        *(u4*)(lds + 8192 + off + 256) = hv1;
    }
    __builtin_amdgcn_s_barrier();

    const int vhalf = (s0 >> 4) & 1;            // position within 32-key perm block
#pragma unroll
    for (int ky = 0; ky < 3; ky++) {
        const char* Al = lds + (ky < 2 ? 0 : 8192);
        const short* Wb = Wf + ky * 65536 + (w * 4) * 512 + lane * 8;
        f4 acc[4];
#pragma unroll
        for (int t = 0; t < 4; t++) acc[t] = (f4){0.f, 0.f, 0.f, 0.f};
#pragma unroll
        for (int k0g = 0; k0g < 8; k0g++) {
            bh8 af  = *(const bh8*)(Al + k0g * 1024 + lane * 16);
            bh8 bf0 = *(const bh8*)(Wb + k0g * 8192);
            bh8 bf1 = *(const bh8*)(Wb + k0g * 8192 + 512);
            bh8 bf2 = *(const bh8*)(Wb + k0g * 8192 + 1024);
            bh8 bf3 = *(const bh8*)(Wb + k0g * 8192 + 1536);
            if (ky < 2) {
                acc[0] = __builtin_amdgcn_mfma_f32_16x16x32_bf16(bf0, af, acc[0], 0, 0, 0);
                acc[1] = __builtin_amdgcn_mfma_f32_16x16x32_bf16(bf1, af, acc[1], 0, 0, 0);
                acc[2] = __builtin_amdgcn_mfma_f32_16x16x32_bf16(bf2, af, acc[2], 0, 0, 0);
                acc[3] = __builtin_amdgcn_mfma_f32_16x16x32_bf16(bf3, af, acc[3], 0, 0, 0);
            } else {
                acc[0] = __builtin_amdgcn_mfma_f32_16x16x32_bf16(af, bf0, acc[0], 0, 0, 0);
                acc[1] = __builtin_amdgcn_mfma_f32_16x16x32_bf16(af, bf1, acc[1], 0, 0, 0);
                acc[2] = __builtin_amdgcn_mfma_f32_16x16x32_bf16(af, bf2, acc[2], 0, 0, 0);
                acc[3] = __builtin_amdgcn_mfma_f32_16x16x32_bf16(af, bf3, acc[3], 0, 0, 0);
            }
        }
        if (ky < 2) {
            // transposed: lane holds P[s = s0+lr][n = w*64+nt*16+lg*4 + 0..3]
            short* P = (ky == 0) ? Q : K;
            const float* bb = (ky == 0) ? bqs : bk;
            const int s = s0 + lr;
#pragma unroll
            for (int nt = 0; nt < 4; nt++) {
                const int nb = w * 64 + nt * 16 + lg * 4;
                const int h = nb >> 5, hd = nb & 31;
                f4 bias = *(const f4*)(bb + nb);
                u2 o = { cvtpk(acc[nt][0] + bias[0], acc[nt][1] + bias[1]),
                         cvtpk(acc[nt][2] + bias[2], acc[nt][3] + bias[3]) };
                *(u2*)(P + ((size_t)(b * Hh + h) * Ssz + s) * HDd + hd) = o;
            }
        } else {
            // normal: lane holds V[s = s0+lg*4 + 0..3][n = w*64+nt*16+lr]
            // k-slot perm within 32-key block: ps = lg*8 + vhalf*4 + r (consecutive in r)
#pragma unroll
            for (int nt = 0; nt < 4; nt++) {
                const int n = w * 64 + nt * 16 + lr;
                const int h = n >> 5, hd = n & 31;
                const float bias = bv[n];
                u2 o = { cvtpk(acc[nt][0] + bias, acc[nt][1] + bias),
                         cvtpk(acc[nt][2] + bias, acc[nt][3] + bias) };
                *(u2*)(Vt + ((size_t)(b * Hh + h) * HDd + hd) * Ssz
                           + (s0 & ~31) + lg * 8 + vhalf * 4) = o;
            }
        }
    }
}

// ---------------- flash attention: 8 waves, 32 q-rows/wave, 3-buffer LDS ----------------
// grid (S/256, B*H, NS), 512 thr. Waves 0-3 stage K, 4-7 stage V (1 gload16/thread/tile).
// 2 Q fragments/wave halve per-MFMA LDS traffic. P = exp2(S-8); denom via ones-MFMA.
template<int NS>
__global__ __launch_bounds__(512, 4) void attn(
    const short* __restrict__ Q, const short* __restrict__ Kb,
    const short* __restrict__ Vt, const float* __restrict__ mask,
    const int* __restrict__ flag, short* __restrict__ ctx,
    short* __restrict__ pacc, float* __restrict__ sums)
{
    __shared__ __align__(16) char lds[24576];    // 3 buffers x (K 4KB + V 4KB)
    const int tid = threadIdx.x;
    const int bh = blockIdx.y, b = bh >> 3, h = bh & 7;
    const int w = tid >> 6, lane = tid & 63;
    const int lg = lane >> 4, lr = lane & 15;
    const int q0 = blockIdx.x * 256 + w * 32;
    const int kz0 = blockIdx.z * (Ssz / NS);
    constexpr int NT = Ssz / NS / 64;

    const char* Kg = (const char*)(Kb + (size_t)bh * Ssz * HDd);
    const char* Vg = (const char*)(Vt + (size_t)bh * HDd * Ssz);
    const bool um = (*flag) != 0;
    const float* mrow0 = mask + ((size_t)b * Ssz + q0 + lr) * Ssz;
    const float* mrow1 = mrow0 + (size_t)16 * Ssz;

    // per-thread staging role: waves 0-3 -> K (4KB), waves 4-7 -> V (4KB)
    const char* sgp;      // per-lane global src for tile 0 (pre-swizzled, rule 21)
    size_t sstep;         // per-tile byte advance
    int ldo;              // wave-uniform LDS offset within buffer
    if (w < 4) {
        const int kt = w * 64 + lane;
        const int kx = (kt * 16) ^ (((kt >> 3) & 3) << 4);
        sgp = Kg + (size_t)kz0 * 64 + kx;
        sstep = 4096;
        ldo = w * 1024;
    } else {
        const int vt2 = (w - 4) * 64 + lane;
        const int vrow = vt2 >> 3;
        const int vcol = ((vt2 & 7) * 16) ^ ((vrow & 7) << 4);
        sgp = Vg + (size_t)vrow * (Ssz * 2) + (size_t)kz0 * 2 + vcol;
        sstep = 128;
        ldo = 4096 + (w - 4) * 1024;
    }

    // swizzled read offsets (within a buffer)
    const int koff  = (lr * 64 + lg * 16) ^ (((lr >> 1) & 3) << 4);
    const int voff0 = 4096 + ((lr * 128 + lg * 16) ^ ((lr & 7) << 4));
    const int voff1 = voff0 ^ 64;

    const short* Qw = Q + ((size_t)bh * Ssz + q0) * HDd;
    bh8 qf0 = *(const bh8*)(Qw + (size_t)lr * HDd + lg * 8);
    bh8 qf1 = *(const bh8*)(Qw + (size_t)(16 + lr) * HDd + lg * 8);
    const f4 c8 = {-8.f, -8.f, -8.f, -8.f};
    f4 a00 = {0.f,0.f,0.f,0.f}, a01 = a00, a10 = a00, a11 = a00;  // [qhalf][hd-half]
    f4 sm0 = a00, sm1 = a00;                 // denominators (ones-MFMA)
    union { unsigned u[4]; bh8 v; } ones;
#pragma unroll
    for (int j = 0; j < 4; j++) ones.u[j] = 0x3F803F80u;

    auto stage = [&](int t, int buf) {
        gload16(sgp + (size_t)t * sstep, lds + buf * 8192 + ldo);
    };

    auto compute = [&](int t, int bs) {
        const char* kp = lds + bs + koff;
        bh8 k0 = *(const bh8*)(kp);
        bh8 k1 = *(const bh8*)(kp + 1024);
        bh8 k2 = *(const bh8*)(kp + 2048);
        bh8 k3 = *(const bh8*)(kp + 3072);
        const char* vp = lds + bs;
        bh8 v00 = *(const bh8*)(vp + voff0);
        bh8 v01 = *(const bh8*)(vp + voff1);
        bh8 v10 = *(const bh8*)(vp + voff0 + 2048);
        bh8 v11 = *(const bh8*)(vp + voff1 + 2048);

        // scores - 8 (log2 domain): D[key][q] + C, q = lr
        __builtin_amdgcn_s_setprio(1);
        f4 s00 = __builtin_amdgcn_mfma_f32_16x16x32_bf16(k0, qf0, c8, 0, 0, 0);
        f4 s01 = __builtin_amdgcn_mfma_f32_16x16x32_bf16(k1, qf0, c8, 0, 0, 0);
        f4 s02 = __builtin_amdgcn_mfma_f32_16x16x32_bf16(k2, qf0, c8, 0, 0, 0);
        f4 s03 = __builtin_amdgcn_mfma_f32_16x16x32_bf16(k3, qf0, c8, 0, 0, 0);
        f4 s10 = __builtin_amdgcn_mfma_f32_16x16x32_bf16(k0, qf1, c8, 0, 0, 0);
        f4 s11 = __builtin_amdgcn_mfma_f32_16x16x32_bf16(k1, qf1, c8, 0, 0, 0);
        f4 s12 = __builtin_amdgcn_mfma_f32_16x16x32_bf16(k2, qf1, c8, 0, 0, 0);
        f4 s13 = __builtin_amdgcn_mfma_f32_16x16x32_bf16(k3, qf1, c8, 0, 0, 0);
        __builtin_amdgcn_s_setprio(0);
        if (um) {
            const int kb = kz0 + t * 64;
            s00 += *(const f4*)(mrow0 + kb + lg * 4) * LOG2E;
            s01 += *(const f4*)(mrow0 + kb + 16 + lg * 4) * LOG2E;
            s02 += *(const f4*)(mrow0 + kb + 32 + lg * 4) * LOG2E;
            s03 += *(const f4*)(mrow0 + kb + 48 + lg * 4) * LOG2E;
            s10 += *(const f4*)(mrow1 + kb + lg * 4) * LOG2E;
            s11 += *(const f4*)(mrow1 + kb + 16 + lg * 4) * LOG2E;
            s12 += *(const f4*)(mrow1 + kb + 32 + lg * 4) * LOG2E;
            s13 += *(const f4*)(mrow1 + kb + 48 + lg * 4) * LOG2E;
        }

        // P = exp2(S - 8), q-half 0 then 1 (limits live registers)
        union { unsigned u[4]; bh8 v; } pf00, pf01, pf10, pf11;
        {
            float p[16];
#pragma unroll
            for (int j = 0; j < 4; j++) {
                p[j] = fexp2(s00[j]); p[4+j] = fexp2(s01[j]);
                p[8+j] = fexp2(s02[j]); p[12+j] = fexp2(s03[j]);
            }
            pf00.u[0] = cvtpk(p[0], p[1]);   pf00.u[1] = cvtpk(p[2], p[3]);
            pf00.u[2] = cvtpk(p[4], p[5]);   pf00.u[3] = cvtpk(p[6], p[7]);
            pf01.u[0] = cvtpk(p[8], p[9]);   pf01.u[1] = cvtpk(p[10], p[11]);
            pf01.u[2] = cvtpk(p[12], p[13]); pf01.u[3] = cvtpk(p[14], p[15]);
        }
        {
            float p[16];
#pragma unroll
            for (int j = 0; j < 4; j++) {
                p[j] = fexp2(s10[j]); p[4+j] = fexp2(s11[j]);
                p[8+j] = fexp2(s12[j]); p[12+j] = fexp2(s13[j]);
            }
            pf10.u[0] = cvtpk(p[0], p[1]);   pf10.u[1] = cvtpk(p[2], p[3]);
            pf10.u[2] = cvtpk(p[4], p[5]);   pf10.u[3] = cvtpk(p[6], p[7]);
            pf11.u[0] = cvtpk(p[8], p[9]);   pf11.u[1] = cvtpk(p[10], p[11]);
            pf11.u[2] = cvtpk(p[12], p[13]); pf11.u[3] = cvtpk(p[14], p[15]);
        }

        __builtin_amdgcn_s_setprio(1);
        a00 = __builtin_amdgcn_mfma_f32_16x16x32_bf16(v00, pf00.v, a00, 0, 0, 0);
        a00 = __builtin_amdgcn_mfma_f32_16x16x32_bf16(v01, pf01.v, a00, 0, 0, 0);
        a01 = __builtin_amdgcn_mfma_f32_16x16x32_bf16(v10, pf00.v, a01, 0, 0, 0);
        a01 = __builtin_amdgcn_mfma_f32_16x16x32_bf16(v11, pf01.v, a01, 0, 0, 0);
        sm0 = __builtin_amdgcn_mfma_f32_16x16x32_bf16(ones.v, pf00.v, sm0, 0, 0, 0);
        sm0 = __builtin_amdgcn_mfma_f32_16x16x32_bf16(ones.v, pf01.v, sm0, 0, 0, 0);
        a10 = __builtin_amdgcn_mfma_f32_16x16x32_bf16(v00, pf10.v, a10, 0, 0, 0);
        a10 = __builtin_amdgcn_mfma_f32_16x16x32_bf16(v01, pf11.v, a10, 0, 0, 0);
        a11 = __builtin_amdgcn_mfma_f32_16x16x32_bf16(v10, pf10.v, a11, 0, 0, 0);
        a11 = __builtin_amdgcn_mfma_f32_16x16x32_bf16(v11, pf11.v, a11, 0, 0, 0);
        sm1 = __builtin_amdgcn_mfma_f32_16x16x32_bf16(ones.v, pf10.v, sm1, 0, 0, 0);
        sm1 = __builtin_amdgcn_mfma_f32_16x16x32_bf16(ones.v, pf11.v, sm1, 0, 0, 0);
        __builtin_amdgcn_s_setprio(0);
    };

    // prologue: two tiles in flight
    stage(0, 0);
    stage(1, 1);
    for (int t = 0; t < NT - 1; ++t) {
        asm volatile("s_waitcnt vmcnt(1)" ::: "memory");   // my stage(t) landed
        __builtin_amdgcn_s_barrier();                       // everyone's landed
        if (t + 2 < NT) stage(t + 2, (t + 2) % 3);          // buf[(t+2)%3] freed by compute(t-1)
        compute(t, (t % 3) * 8192);
    }
    asm volatile("s_waitcnt vmcnt(0)" ::: "memory");
    __builtin_amdgcn_s_barrier();
    compute(NT - 1, ((NT - 1) % 3) * 8192);

    const float sum0 = sm0[0], sum1 = sm1[0];   // D[row][q=lr] identical for all rows

    if constexpr (NS == 1) {
        float inv0 = 1.f / sum0, inv1 = 1.f / sum1;
        short* cp0 = ctx + ((size_t)(b * Ssz + q0 + lr)) * Dsz + h * HDd + lg * 4;
        short* cp1 = cp0 + (size_t)16 * Dsz;
#pragma unroll
        for (int r = 0; r < 4; r++) {
            cp0[r]      = f2bf(a00[r] * inv0);
            cp0[16 + r] = f2bf(a01[r] * inv0);
            cp1[r]      = f2bf(a10[r] * inv1);
            cp1[16 + r] = f2bf(a11[r] * inv1);
        }
    } else {
        // raw (unnormalized) partials; equal static offsets -> combine is a simple sum
        const size_t rbase = ((size_t)blockIdx.z * (Bsz * Hh) + bh) * Ssz + q0 + lr;
        short* pa0 = pacc + rbase * HDd;
        short* pa1 = pa0 + (size_t)16 * HDd;
        *(u2*)(pa0 + lg * 4)      = (u2){cvtpk(a00[0], a00[1]), cvtpk(a00[2], a00[3])};
        *(u2*)(pa0 + 16 + lg * 4) = (u2){cvtpk(a01[0], a01[1]), cvtpk(a01[2], a01[3])};
        *(u2*)(pa1 + lg * 4)      = (u2){cvtpk(a10[0], a10[1]), cvtpk(a10[2], a10[3])};
        *(u2*)(pa1 + 16 + lg * 4) = (u2){cvtpk(a11[0], a11[1]), cvtpk(a11[2], a11[3])};
        if (lg == 0) {
            sums[rbase]      = sum0;
            sums[rbase + 16] = sum1;
        }
    }
}

// ---------------- output projection; SPLIT=1 fuses the split-KV combine ----------------
// block = 16-row tile, wave = 64-col quarter; transposed mfma -> f4 coalesced stores.
template<int SPLIT>
__global__ __launch_bounds__(256) void out_gemm(
    const short* __restrict__ ctx, const short* __restrict__ pacc,
    const float* __restrict__ sums, const short* __restrict__ WfO,
    const float* __restrict__ bo, float* __restrict__ out)
{
    const int w = threadIdx.x >> 6, lane = threadIdx.x & 63;
    const int lg = lane >> 4, lr = lane & 15;
    const int m0 = blockIdx.x * 16;
    const int row = m0 + lr;                 // global (b,q) row
    const int b = row >> 11, q = row & 2047;
    f4 acc[4];
#pragma unroll
    for (int t = 0; t < 4; t++) acc[t] = (f4){0.f, 0.f, 0.f, 0.f};
    const short* ap = ctx + (size_t)row * 256 + lg * 8;
    const short* Wb = WfO + (w * 4) * 512 + lane * 8;
    constexpr size_t R = (size_t)(Bsz * Hh) * Ssz;   // rows per split half
#pragma unroll
    for (int k0g = 0; k0g < 8; k0g++) {
        union { unsigned u[4]; bh8 v; } af;
        if constexpr (SPLIT) {
            const int h = k0g;
            const size_t pr = ((size_t)(b * Hh + h)) * Ssz + q;
            const float inv = 1.f / (sums[pr] + sums[R + pr]);
            bh8 x0 = *(const bh8*)(pacc + pr * HDd + lg * 8);
            bh8 x1 = *(const bh8*)(pacc + (R + pr) * HDd + lg * 8);
            af.u[0] = cvtpk((bf2f(x0[0]) + bf2f(x1[0])) * inv, (bf2f(x0[1]) + bf2f(x1[1])) * inv);
            af.u[1] = cvtpk((bf2f(x0[2]) + bf2f(x1[2])) * inv, (bf2f(x0[3]) + bf2f(x1[3])) * inv);
            af.u[2] = cvtpk((bf2f(x0[4]) + bf2f(x1[4])) * inv, (bf2f(x0[5]) + bf2f(x1[5])) * inv);
            af.u[3] = cvtpk((bf2f(x0[6]) + bf2f(x1[6])) * inv, (bf2f(x0[7]) + bf2f(x1[7])) * inv);
        } else {
            af.v = *(const bh8*)(ap + k0g * 32);
        }
#pragma unroll
        for (int nt = 0; nt < 4; nt++) {
            bh8 bf = *(const bh8*)(Wb + k0g * 8192 + nt * 512);
            acc[nt] = __builtin_amdgcn_mfma_f32_16x16x32_bf16(bf, af.v, acc[nt], 0, 0, 0);
        }
    }
    // transposed C: lane holds out[row = m0+lr][n = w*64+nt*16+lg*4 + 0..3] -> f4 store
#pragma unroll
    for (int nt = 0; nt < 4; nt++) {
        const int nb = w * 64 + nt * 16 + lg * 4;
        f4 bias = *(const f4*)(bo + nb);
        f4 res = acc[nt] + bias;
        *(f4*)(out + (size_t)row * 256 + nb) = res;
    }
}

extern "C" void kernel_launch(void* const* d_in, const int* in_sizes, int n_in,
                              void* d_out, int out_size, void* d_ws, size_t ws_size,
                              hipStream_t stream)
{
    const float* hid  = (const float*)d_in[0];
    const float* pos  = (const float*)d_in[1];
    const float* mask = (const float*)d_in[2];
    const float* Wq   = (const float*)d_in[3];
    const float* bq   = (const float*)d_in[4];
    const float* Wk   = (const float*)d_in[5];
    const float* bk   = (const float*)d_in[6];
    const float* Wv   = (const float*)d_in[7];
    const float* bv   = (const float*)d_in[8];
    const float* Wo   = (const float*)d_in[9];
    const float* bo   = (const float*)d_in[10];
    float* out = (float*)d_out;

    char* ws = (char*)d_ws;
    short* Wf   = (short*)(ws);                    // 512 KB fragment-packed weights
    float* bqs  = (float*)(ws + (512 << 10));      // 1 KB
    int*   flag = (int*)  (ws + (516 << 10));      // 4 B
    short* Qb   = (short*)(ws + (9  << 20));       // 4 MB  [B,H,S,32]
    short* Kb   = (short*)(ws + (13 << 20));       // 4 MB  [B,H,S,32]
    short* Vtb  = (short*)(ws + (17 << 20));       // 4 MB  [B,H,32,S] (k-slot permuted)
    short* ctxb = (short*)(ws + (21 << 20));       // 4 MB  [B,S,256] (NS=1 path only)
    short* pacc = (short*)(ws + (25 << 20));       // 8.4 MB [2,B*H,S,32] raw partials
    float* sums = (float*)(ws + (34 << 20));       // 512 KB [2,B*H,S]

    prep_fast<<<256, 256, 0, stream>>>(Wq, Wk, Wv, Wo, bq, Wf, bqs, flag);
    qkv_scan<<<1536, 256, 0, stream>>>(hid, pos, Wf, bqs, bk, bv, mask, flag, Qb, Kb, Vtb);

    const bool split = ws_size >= ((size_t)36 << 20);
    if (split) {
        attn<2><<<dim3(8, 32, 2), 512, 0, stream>>>(Qb, Kb, Vtb, mask, flag, ctxb, pacc, sums);
        out_gemm<1><<<512, 256, 0, stream>>>(ctxb, pacc, sums, Wf + 196608, bo, out);
    } else {
        attn<1><<<dim3(8, 32, 1), 512, 0, stream>>>(Qb, Kb, Vtb, mask, flag, ctxb, pacc, sums);
        out_gemm<0><<<512, 256, 0, stream>>>(ctxb, pacc, sums, Wf + 196608, bo, out);
    }
}